// Round 5
// baseline (22.154 us; speedup 1.0000x reference)
//
#include <hip/hip_runtime.h>

// ECT: out[b,c,r,t] = sum_{n in (b,c)} sigmoid(SCALE*(lin[r] - x[n].v[:,t])), max-normalized per (b,c).
// Window trick (validated r1-r3): sigmoid saturates within ~3 bins (SCALE=100, bin=2/63).
// Delta encoding along r: per point add d(lo)=s0, d(lo+u)=s_u - s_{u-1} (u=1..3), d(lo+4)=1-s3
// (all >= 0, fixed-point 2^20, native ds_add_u32); inclusive prefix over r reconstructs window+tail.
// 512 small blocks (seg x 4 slices) write partial grids to ws; finalize kernel sums+scans+normalizes.

constexpr int T   = 64;
constexpr int RES = 64;
constexpr float RADIUS = 1.0f;
constexpr float SCALE  = 100.0f;
constexpr float LOG2E  = 1.44269504088896340736f;

#define TP      256            // part-kernel threads (4 waves)
#define NWP     4
#define NSLICE  4
#define ACCW    71             // acc row stride in words (odd -> 2-way banks max)
#define TK      512            // table rows
#define FPSCALE 1048576.0f     // 2^20
#define FPQ     1048576u
#define FPINV   (1.0f / 1048576.0f)

__global__ __launch_bounds__(TP) void ect_part(
    const float* __restrict__ x, const float* __restrict__ v,
    const int* __restrict__ index, const int* __restrict__ channels,
    unsigned* __restrict__ ws, int N)
{
  __shared__ unsigned acc[T * ACCW];              // [t][row], rows 0..68 used
  __shared__ alignas(16) unsigned tblD[TK * 4];   // window deltas d0..d3
  __shared__ unsigned tblE[TK];                   // tail delta d4 = FPQ - s3
  __shared__ int l_bounds[2];

  const int blk  = blockIdx.x;
  const int seg  = blk >> 2;            // NSLICE == 4
  const int sl   = blk & 3;
  const int b    = seg >> 2;            // MAX_CHANNELS == 4
  const int c    = seg & 3;
  const int tid  = threadIdx.x;
  const int lane = tid & 63;
  const int wv   = tid >> 6;

  const float S2D  = SCALE * LOG2E * (2.0f * RADIUS / (RES - 1));
  const float invD = (RES - 1) / (2.0f * RADIUS);   // 31.5

  for (int i = tid; i < T * ACCW; i += TP) acc[i] = 0u;

  // build delta table: f = (q+0.5)/TK; s_k = sigmoid in log2 domain
  for (int i = tid; i < TK * 5; i += TP) {
    const int   q = i / 5, u = i - q * 5;
    const float f = (q + 0.5f) * (1.0f / TK);
    unsigned qcur, qprev = 0u;
    {
      float e = __builtin_amdgcn_exp2f(S2D * (1.0f + f - (float)min(u, 3)));
      qcur = (unsigned)(FPSCALE / (1.0f + e) + 0.5f);
    }
    if (u > 0) {
      float e = __builtin_amdgcn_exp2f(S2D * (1.0f + f - (float)(min(u, 4) - 1)));
      qprev = (unsigned)(FPSCALE / (1.0f + e) + 0.5f);
    }
    if (u < 4) tblD[q * 4 + u] = qcur - qprev;
    else       tblE[q]         = FPQ - qprev;     // u==4: prev = s3
  }

  // wave-parallel 64-ary search for batch bounds (waves 0,1)
  if (wv < 2) {
    const int tg = b + wv;
    int lo = 0, len = N;
    while (len > 64) {
      int step = (len + 63) >> 6;
      int p = lo + lane * step;
      bool lt = (p < lo + len) && (index[p] < tg);
      unsigned long long mask = __ballot(lt);
      if (mask) lo += (63 - __clzll(mask)) * step + 1;
      len = min(step, N - lo);
    }
    int p = lo + lane;
    bool ge = (lane < len) && (index[p] >= tg);
    unsigned long long mask = __ballot(ge);
    int ans = mask ? (lo + (int)__builtin_ctzll(mask)) : (lo + len);
    if (lane == 0) l_bounds[wv] = ans;
  }
  __syncthreads();

  const int s0  = l_bounds[0], s1 = l_bounds[1];
  const int len = s1 - s0;
  const int p0  = s0 + (len * sl) / NSLICE;
  const int p1  = s0 + (len * (sl + 1)) / NSLICE;

  // per-lane direction t = lane; fold invD into weights
  const float w0 = v[0 * T + lane] * invD;
  const float w1 = v[1 * T + lane] * invD;
  const float w2 = v[2 * T + lane] * invD;
  unsigned* const arow = &acc[lane * ACCW];

  for (int gb = p0 + wv * 64; gb < p1; gb += NWP * 64) {
    const int  pt    = gb + lane;
    const bool valid = pt < p1;
    int   ch = -1;
    float px = 0.f, py = 0.f, pz = 0.f;
    if (valid) {
      ch = channels[pt];
      px = x[pt * 3 + 0];
      py = x[pt * 3 + 1];
      pz = x[pt * 3 + 2];
    }
    unsigned long long mask = __ballot(ch == c);
    while (mask) {
      const int j = (int)__builtin_ctzll(mask);
      mask &= mask - 1;
      const float qx = __int_as_float(__builtin_amdgcn_readlane(__float_as_int(px), j));
      const float qy = __int_as_float(__builtin_amdgcn_readlane(__float_as_int(py), j));
      const float qz = __int_as_float(__builtin_amdgcn_readlane(__float_as_int(pz), j));
      const float g  = fmaf(qx, w0, fmaf(qy, w1, fmaf(qz, w2, invD)));  // (nh+1)*31.5
      const float gf = floorf(g);
      int fq = (int)((g - gf) * (float)TK);
      fq = min(fq, TK - 1);
      const int lo  = (int)gf - 1;
      const int loc = min(max(lo, -4), 64);        // positions loc..loc+4 in [-4,68]
      const uint4 tv = *(const uint4*)&tblD[fq << 2];
      const unsigned te = tblE[fq];
      atomicAdd(&arow[max(loc + 0, 0)], tv.x);
      atomicAdd(&arow[max(loc + 1, 0)], tv.y);
      atomicAdd(&arow[max(loc + 2, 0)], tv.z);
      atomicAdd(&arow[max(loc + 3, 0)], tv.w);
      atomicAdd(&arow[max(loc + 4, 0)], te);
    }
  }
  __syncthreads();

  // flush partial grid (rows 0..63) to ws[blk][t*64+r], plain coalesced stores
  unsigned* const wout = ws + (size_t)blk * (T * RES);
  for (int i = tid; i < T * RES; i += TP) {
    const int t = i >> 6, r = i & 63;
    wout[i] = acc[t * ACCW + r];
  }
}

__global__ __launch_bounds__(1024) void ect_fin(
    const unsigned* __restrict__ ws, float* __restrict__ out)
{
  __shared__ float fin[RES * 65];
  __shared__ float wmax[16];
  __shared__ float s_scale;
  const int seg  = blockIdx.x;
  const int tid  = threadIdx.x;
  const int lane = tid & 63;
  const int wv   = tid >> 6;
  const unsigned* const wsg = ws + (size_t)seg * NSLICE * (T * RES);

  #pragma unroll
  for (int u2 = 0; u2 < 4; ++u2) {
    const int t = (wv << 2) | u2;
    unsigned h = 0u;
    #pragma unroll
    for (int s = 0; s < NSLICE; ++s) h += wsg[s * (T * RES) + t * 64 + lane];  // lane = r
    #pragma unroll
    for (int d = 1; d < 64; d <<= 1) {
      unsigned o = __shfl_up(h, (unsigned)d);
      if (lane >= d) h += o;
    }
    fin[lane * 65 + t] = (float)h * FPINV;
  }
  __syncthreads();

  float vals[4];
  float mx = 0.0f;
  #pragma unroll
  for (int k = 0; k < 4; ++k) {
    const int r = wv + k * 16;            // flat = tid + k*1024 -> r, t = lane
    vals[k] = fin[r * 65 + lane];
    mx = fmaxf(mx, vals[k]);
  }
  #pragma unroll
  for (int s = 32; s >= 1; s >>= 1) mx = fmaxf(mx, __shfl_xor(mx, s));
  if (lane == 0) wmax[wv] = mx;
  __syncthreads();
  if (tid == 0) {
    float m2 = wmax[0];
    #pragma unroll
    for (int i = 1; i < 16; ++i) m2 = fmaxf(m2, wmax[i]);
    s_scale = (m2 > 0.0f) ? 1.0f / m2 : 1.0f;
  }
  __syncthreads();
  const float sc = s_scale;
  float* const o = out + (size_t)seg * (RES * T);
  #pragma unroll
  for (int k = 0; k < 4; ++k) o[tid + k * 1024] = vals[k] * sc;
}

extern "C" void kernel_launch(void* const* d_in, const int* in_sizes, int n_in,
                              void* d_out, int out_size, void* d_ws, size_t ws_size,
                              hipStream_t stream) {
  const float* x        = (const float*)d_in[0];
  const float* v        = (const float*)d_in[1];
  const int*   index    = (const int*)d_in[2];
  const int*   channels = (const int*)d_in[3];
  float*       out      = (float*)d_out;
  unsigned*    ws       = (unsigned*)d_ws;
  const int N    = in_sizes[2];              // 32768
  const int nseg = out_size / (RES * T);     // 128

  hipLaunchKernelGGL(ect_part, dim3(nseg * NSLICE), dim3(TP), 0, stream,
                     x, v, index, channels, ws, N);
  hipLaunchKernelGGL(ect_fin, dim3(nseg), dim3(1024), 0, stream, ws, out);
}